// Round 1
// 145.779 us; speedup vs baseline: 1.0070x; 1.0070x over previous
//
#include <hip/hip_runtime.h>

// B=4, C=256, N=4096 attention modulation.
// out[b,c,i] = newL[b,i]*src[b,c,i] + newB[b,i],
// newL[b,i] = sum_j softmax_j(E)*oldL[j], E = src_i . ref_j over C.
//
// R13 (theory: flash is serialization-bound at 1 block/CU, not pipe-bound;
// remainder moves ~3x the necessary bytes):
//  (a) flash: 4-tile phases (2 x 64KB LDS double buffer = 128KB of the
//      160KB/CU). Barriers 32 -> 8 per CU; tile t's exp/accumulate VALU
//      loop is independent of tile t+1's MFMA chain, so the unrolled
//      phase body lets the scheduler co-issue the two pipes in-wave
//      (2-3 waves/SIMD can't do it across waves).
//  (b) flash self-builds A-fragments from fp32 src (coalesced 2x128B row
//      loads per (kb,e), one-time per wave) -> s16 and its prep pass die.
//  (c) prep: 1x1 conv fused into the ref-transpose blocks (tile already
//      in LDS) via partials + atomicAdd; bias folded into flash.
//  (d) flash accumulates sumP/sumL/sumB via atomicAdd (memset'd ws);
//      post reads 3 float4 instead of 24 (part re-read was 25MB).
//  JSLICE 8 -> 4, grid 256 = exactly 1 block/CU, NT=32 tiles/block.

#define B_ 4
#define C_ 256
#define N_ 4096
#define LOG2E 1.44269504f
#define SHIFT2 86.5617f      // 60 * log2(e)
#define JSLICE 4
#define BN_ (B_ * N_)
#define NT_ 32               // j-tiles per block (1024 j)
#define PH_ 8                // phases of 4 tiles

typedef _Float16 half_t;
typedef _Float16 v8h  __attribute__((ext_vector_type(8)));
typedef float    v16f __attribute__((ext_vector_type(16)));

#define GLDS16(g, l) __builtin_amdgcn_global_load_lds(                         \
    (const __attribute__((address_space(1))) void*)(g),                        \
    (__attribute__((address_space(3))) void*)(l), 16, 0, 0)

// --------------------- prep: ref transpose to fp16 fragments + fused conv
// grid (N/64, C/64, B), block 256.
// fragment layout t16[b][tile=n/32][kb=c/16][lane][e],
//   lane=((c>>3)&1)*32+(n&31), e=c&7.
// conv: partial over this block's 64 channels -> atomicAdd into oldL/oldB
// (zeroed by memset; bias added in k_flash).
__global__ void k_prep(const float* __restrict__ ref,
                       const float* __restrict__ wl,
                       const float* __restrict__ wb,
                       half_t* __restrict__ r16,
                       float* __restrict__ oldL, float* __restrict__ oldB) {
    __shared__ float tile[64][65];
    __shared__ float red[8][64];
    int b  = blockIdx.z;
    int c0 = blockIdx.y * 64;
    int n0 = blockIdx.x * 64;
    int tid = threadIdx.x;
    int tx = tid & 15, ty = tid >> 4;
#pragma unroll
    for (int q = 0; q < 4; q++) {
        int c = ty + q * 16;
        float4 v = *(const float4*)(ref + ((size_t)b * C_ + c0 + c) * N_ + n0 + tx * 4);
        tile[c][tx * 4 + 0] = v.x;
        tile[c][tx * 4 + 1] = v.y;
        tile[c][tx * 4 + 2] = v.z;
        tile[c][tx * 4 + 3] = v.w;
    }
    __syncthreads();
    // fragment write
    int r   = tid & 31;
    int lhi = (tid >> 5) & 1;
    int wv  = tid >> 6;                  // kb_local 0..3
#pragma unroll
    for (int nt = 0; nt < 2; nt++) {
        int nl = nt * 32 + r;
        v8h o;
#pragma unroll
        for (int e = 0; e < 8; e++)
            o[e] = (half_t)tile[wv * 16 + lhi * 8 + e][nl];
        size_t tj = (size_t)(n0 >> 5) + nt;
        size_t kb = (size_t)(c0 >> 4) + wv;
        *(v8h*)(r16 + ((((size_t)b * 128 + tj) * 16 + kb) * 64 + (tid & 63)) * 8) = o;
    }
    // fused 1x1-conv partial over this block's 64 channels
    int n  = tid & 63;
    int cq = tid >> 6;                   // 0..3
    float aL = 0.f, aB = 0.f;
#pragma unroll
    for (int c = 0; c < 16; c++) {
        float v = tile[cq * 16 + c][n];
        aL += v * wl[c0 + cq * 16 + c];
        aB += v * wb[c0 + cq * 16 + c];
    }
    red[cq][n]     = aL;
    red[4 + cq][n] = aB;
    __syncthreads();
    if (tid < 64) {
        atomicAdd(&oldL[(size_t)b * N_ + n0 + tid],
                  red[0][tid] + red[1][tid] + red[2][tid] + red[3][tid]);
    } else if (tid < 128) {
        int u = tid - 64;
        atomicAdd(&oldB[(size_t)b * N_ + n0 + u],
                  red[4][u] + red[5][u] + red[6][u] + red[7][u]);
    }
}

// ------------------------------------------------------------------ flash
// grid 256 = B(4) x jslice(4) x iblock(16), block 512 = 8 waves.
// Wave owns 32 i-rows; A-fragments built in-kernel from fp32 src (one-time).
// 4 j-tiles per phase staged by global_load_lds into a 2 x 64KB double
// buffer; per phase the 4 unrolled tile bodies give the scheduler
// independent MFMA chains to overlap with the previous tile's exp loop.
__global__ __launch_bounds__(512, 2) void k_flash(
        const float* __restrict__ src, const half_t* __restrict__ rT,
        const float* __restrict__ oldL, const float* __restrict__ oldB,
        const float* __restrict__ bl, const float* __restrict__ bb,
        float* __restrict__ sumP, float* __restrict__ sumL,
        float* __restrict__ sumB) {
    __shared__ half_t lds[2][32768];     // 2 x 64KB (4 tiles each)
    int bid    = blockIdx.x;
    int b      = bid & 3;                // XCD spread
    int jslice = (bid >> 2) & (JSLICE - 1);
    int iblock = bid >> 4;
    int tid    = threadIdx.x;
    int wv     = tid >> 6;               // 0..7
    int lane   = tid & 63;
    int l31    = lane & 31, lhi = lane >> 5;
    int ti     = iblock * 8 + wv;        // 32-row A tile index
    int i0     = ti * 32;
    int j0     = jslice * (N_ / JSLICE); // 1024 j per block
    int tj0    = j0 >> 5;

    // A fragments built from fp32 src: a[kb][e] = src[b][kb*16+lhi*8+e][i0+l31]
    // * log2e. Each (kb,e) load is 2 x 128B coalesced segments; 128
    // independent loads, one-time per wave, amortized over 32 j-tiles.
    const float* aS = src + (size_t)b * C_ * N_ + i0 + l31;
    v8h a[16];
#pragma unroll
    for (int kb = 0; kb < 16; kb++) {
        v8h o;
#pragma unroll
        for (int e = 0; e < 8; e++)
            o[e] = (half_t)(aS[(size_t)(kb * 16 + lhi * 8 + e) * N_] * LOG2E);
        a[kb] = o;
    }

    const half_t* bBase = rT + (((size_t)b * 128 + tj0) * 16) * 512;  // block-uniform
    const float*  oLp = oldL + (size_t)b * N_ + j0 + l31;
    const float*  oBp = oldB + (size_t)b * N_ + j0 + l31;
    float bl0 = bl[0], bb0 = bb[0];

    float sp[16], sl[16], sb[16];
#pragma unroll
    for (int r = 0; r < 16; r++) { sp[r] = 0.f; sl[r] = 0.f; sb[r] = 0.f; }

    // Prologue: DMA phase 0 (4 tiles = 64 chunks of 1KB) into buffer 0.
#pragma unroll
    for (int q = 0; q < 8; q++) {
        int chunk = q * 8 + wv;
        GLDS16(bBase + (size_t)chunk * 512 + (size_t)lane * 8,
               &lds[0][(size_t)chunk * 512]);
    }

    for (int ph = 0; ph < PH_; ph++) {
        __syncthreads();                       // drains DMA -> buf[ph&1] ready
        if (ph + 1 < PH_) {                    // DMA next 4-tile phase
            const half_t* g = bBase + (size_t)(ph + 1) * 32768;
#pragma unroll
            for (int q = 0; q < 8; q++) {
                int chunk = q * 8 + wv;
                GLDS16(g + (size_t)chunk * 512 + (size_t)lane * 8,
                       &lds[(ph + 1) & 1][(size_t)chunk * 512]);
            }
        }
        float lamv[4], betv[4];
#pragma unroll
        for (int t = 0; t < 4; t++) {
            lamv[t] = oLp[(ph * 4 + t) * 32] + bl0;
            betv[t] = oBp[(ph * 4 + t) * 32] + bb0;
        }
        const half_t* btb = lds[ph & 1] + (size_t)lane * 8;
#pragma unroll
        for (int t = 0; t < 4; t++) {
            const half_t* bt = btb + (size_t)t * 8192;
            // Two independent 8-deep MFMA chains per tile; tiles within the
            // phase are mutually independent -> exp loop of tile t overlaps
            // MFMA of tile t+1.
            v16f acc0, acc1;
#pragma unroll
            for (int r = 0; r < 16; r++) { acc0[r] = -SHIFT2; acc1[r] = 0.f; }
#pragma unroll
            for (int kb = 0; kb < 8; kb++) {
                acc0 = __builtin_amdgcn_mfma_f32_32x32x16_f16(
                    a[kb],     *(const v8h*)(bt + (size_t)kb * 512),       acc0, 0, 0, 0);
                acc1 = __builtin_amdgcn_mfma_f32_32x32x16_f16(
                    a[kb + 8], *(const v8h*)(bt + (size_t)(kb + 8) * 512), acc1, 0, 0, 0);
            }
            float lam = lamv[t], bet = betv[t];
#pragma unroll
            for (int r = 0; r < 16; r++) {
                float p = __builtin_amdgcn_exp2f(acc0[r] + acc1[r]);
                sp[r] += p;
                sl[r] += p * lam;
                sb[r] += p * bet;
            }
        }
    }

#pragma unroll
    for (int r = 0; r < 16; r++) {
        float tp = sp[r], tl = sl[r], tb = sb[r];
#pragma unroll
        for (int m = 1; m <= 16; m <<= 1) {
            tp += __shfl_xor(tp, m, 64);
            tl += __shfl_xor(tl, m, 64);
            tb += __shfl_xor(tb, m, 64);
        }
        if (l31 == 0) {
            // C/D layout: row = (reg&3) + 8*(reg>>2) + 4*(lane>>5)
            int row = (r & 3) + 8 * (r >> 2) + 4 * lhi;
            size_t ig = (size_t)b * N_ + i0 + row;
            atomicAdd(&sumP[ig], tp);
            atomicAdd(&sumL[ig], tl);
            atomicAdd(&sumB[ig], tb);
        }
    }
}

// ------------------------- epilogue: normalize + modulate
// grid (B, N/1024, C/16), block 256. Thread owns 4 consecutive pixels:
// newL/newB from the 3 sum arrays (one float4 each), then a 16-channel
// sweep with 4KB-contiguous float4 lines.
__global__ void k_post(const float* __restrict__ src,
                       const float* __restrict__ sumP,
                       const float* __restrict__ sumL,
                       const float* __restrict__ sumB,
                       float* __restrict__ out) {
    int b  = blockIdx.x;
    int n0 = blockIdx.y * 1024;
    int c0 = blockIdx.z * 16;
    int t  = threadIdx.x;
    size_t bn = (size_t)b * N_ + n0 + t * 4;
    float4 sp = *(const float4*)(sumP + bn);
    float4 sl = *(const float4*)(sumL + bn);
    float4 sb = *(const float4*)(sumB + bn);
    float4 L, T;
    L.x = sl.x / sp.x; L.y = sl.y / sp.y; L.z = sl.z / sp.z; L.w = sl.w / sp.w;
    T.x = sb.x / sp.x; T.y = sb.y / sp.y; T.z = sb.z / sp.z; T.w = sb.w / sp.w;
    const float* sp0 = src + ((size_t)b * C_ + c0) * N_ + n0 + t * 4;
    float*       op0 = out + ((size_t)b * C_ + c0) * N_ + n0 + t * 4;
#pragma unroll 4
    for (int c = 0; c < 16; c++) {
        float4 v = *(const float4*)(sp0 + (size_t)c * N_);
        float4 o;
        o.x = L.x * v.x + T.x;
        o.y = L.y * v.y + T.y;
        o.z = L.z * v.z + T.z;
        o.w = L.w * v.w + T.w;
        *(float4*)(op0 + (size_t)c * N_) = o;
    }
}

extern "C" void kernel_launch(void* const* d_in, const int* in_sizes, int n_in,
                              void* d_out, int out_size, void* d_ws, size_t ws_size,
                              hipStream_t stream) {
    const float* src = (const float*)d_in[0];
    const float* ref = (const float*)d_in[1];
    const float* wl  = (const float*)d_in[2];
    const float* bl  = (const float*)d_in[3];
    const float* wb  = (const float*)d_in[4];
    const float* bb  = (const float*)d_in[5];
    float* out = (float*)d_out;

    float* oldL = (float*)d_ws;
    float* oldB = oldL + BN_;
    float* sumP = oldB + BN_;
    float* sumL = sumP + BN_;
    float* sumB = sumL + BN_;
    size_t needF  = (size_t)5 * BN_ * sizeof(float);
    size_t need16 = (size_t)B_ * N_ * C_ * sizeof(half_t);
    half_t* r16;
    if (ws_size >= needF + need16) r16 = (half_t*)((char*)d_ws + needF);
    else                           r16 = (half_t*)d_out;   // dead before k_post writes

    hipMemsetAsync(d_ws, 0, needF, stream);   // zero oldL/oldB + sum accumulators
    k_prep<<<dim3(N_ / 64, C_ / 64, B_), 256, 0, stream>>>(
        ref, wl, wb, r16, oldL, oldB);
    k_flash<<<B_ * JSLICE * 16, 512, 0, stream>>>(
        src, r16, oldL, oldB, bl, bb, sumP, sumL, sumB);
    k_post<<<dim3(B_, N_ / 1024, C_ / 16), 256, 0, stream>>>(
        src, sumP, sumL, sumB, out);
}